// Round 5
// baseline (359.815 us; speedup 1.0000x reference)
//
#include <hip/hip_runtime.h>

// Problem constants: B=8, C=4, H=W=512, K_ITERS=10, ALPHA=2
#define Wd   512
#define W4   128               // float4s per row
#define HWp  262144            // elements per (b,c) plane
#define NTOT 8388608           // B*C*H*W

#define F_INF __int_as_float(0x7F800000)

// red[] layout (960 floats, ALL zero-init; per-iteration slots):
//   cmn[k][plane] = red[k*32 + plane]        unsigned ~bits(min)
//   mx [k][plane] = red[320 + k*32 + plane]  float bits, signed atomicMax
//   sm [k][plane] = red[640 + k*32 + plane]  float atomicAdd

__device__ __forceinline__ float4 bound4(const float* __restrict__ pred,
                                         const int* __restrict__ target,
                                         int plane, int v)
{
    const int b = plane >> 2, c = plane & 3;
    float4 p = ((const float4*)(pred + (size_t)plane * HWp))[v];
    int4   t = ((const int4*)(target + (size_t)b * HWp))[v];
    float dx = p.x - (t.x == c ? 1.0f : 0.0f);
    float dy = p.y - (t.y == c ? 1.0f : 0.0f);
    float dz = p.z - (t.z == c ? 1.0f : 0.0f);
    float dw = p.w - (t.w == c ? 1.0f : 0.0f);
    return make_float4(dx*dx, dy*dy, dz*dz, dw*dw);
}

__device__ __forceinline__ float bound1(const float* __restrict__ pred,
                                        const int* __restrict__ target,
                                        int plane, int i)
{
    const int b = plane >> 2, c = plane & 3;
    float p = pred[(size_t)plane * HWp + i];
    int   t = target[(size_t)b * HWp + i];
    float d = p - (t == c ? 1.0f : 0.0f);
    return d * d;
}

// One erosion pass. Grid: 64 chunks (8 rows) x 32 planes = 2048 blocks of
// 256 -> 8 blocks/CU (launch_bounds(256,8) caps VGPR at 64) = 100%
// occupancy. Each thread owns 4 consecutive rows and issues ALL loads up
// front (6 float4 + 8 halo scalars = 14 independent requests in flight)
// before any compute -- this is the MLP that hides the L3 round-trip
// latency (round 3: 2 loads in flight = 4x slower; round 0: 5/step = ok).
// Arithmetic identical to the verified round-0 kernel.
template <bool FIRST>
__global__ __launch_bounds__(256, 8) void stencil_k(const float* __restrict__ in,
                                                    float* __restrict__ out,
                                                    const float* __restrict__ pred,
                                                    const int* __restrict__ target,
                                                    float* __restrict__ red,
                                                    int k, int store)
{
    const int plane = blockIdx.y;
    const int chunk = blockIdx.x;              // 8 rows per chunk

    float s = 1.0f, o = 0.0f;
    if (!FIRST) {
        float mn = __uint_as_float(~((const unsigned*)red)[(k - 1) * 32 + plane]);
        float mx = red[320 + (k - 1) * 32 + plane];
        float denom = mx - mn;
        if (denom != 0.0f) { s = 1.0f / denom; o = -mn / denom; }
    }

    const float* ip = FIRST ? (const float*)nullptr : in + (size_t)plane * HWp;
    float*       op = out + (size_t)plane * HWp;

    const int col4 = threadIdx.x & 127;        // float4 column 0..127
    const int rsub = threadIdx.x >> 7;         // 0..1
    const int row0 = chunk * 8 + rsub * 4;     // 4 rows per thread
    const int v0   = row0 * W4 + col4;

    const bool hasL  = (col4 > 0);
    const bool hasR  = (col4 < W4 - 1);
    const bool hasU0 = (row0 > 0);             // up-halo exists
    const bool hasD3 = (row0 + 4 < Wd);        // down-halo exists

    auto LD4 = [&](int v) -> float4 {
        if constexpr (FIRST) return bound4(pred, target, plane, v);
        else                 return ((const float4*)ip)[v];
    };
    auto LD1 = [&](int i) -> float {
        if constexpr (FIRST) return bound1(pred, target, plane, i);
        else                 return ip[i];
    };

    // ---- issue every load up front (14 independent requests) ----
    float4 u  = hasU0 ? LD4(v0 - W4)     : make_float4(0, 0, 0, 0);
    float4 c0 = LD4(v0);
    float4 c1 = LD4(v0 + W4);
    float4 c2 = LD4(v0 + 2 * W4);
    float4 c3 = LD4(v0 + 3 * W4);
    float4 d  = hasD3 ? LD4(v0 + 4 * W4) : make_float4(0, 0, 0, 0);
    float lf[4], rg[4];
    #pragma unroll
    for (int i = 0; i < 4; i++) {
        lf[i] = hasL ? LD1(4 * (v0 + i * W4) - 1) : 0.0f;
        rg[i] = hasR ? LD1(4 * (v0 + i * W4) + 4) : 0.0f;
    }

    float lmin = F_INF, lmax = 0.0f, lsum = 0.0f;

    auto ROW = [&](const float4& u4, const float4& c4, const float4& d4,
                   float lft, float rgt, bool hU, bool hD, int v) {
        const float vc = (hU ? 1.0f : 0.0f) + (hD ? 1.0f : 0.0f);
        float4 sum, cnt;
        sum.x = c4.x + c4.y + u4.x + d4.x + lft;
        cnt.x = 2.0f + (hasL ? 1.0f : 0.0f) + vc;
        sum.y = c4.x + c4.y + c4.z + u4.y + d4.y;
        cnt.y = 3.0f + vc;
        sum.z = c4.y + c4.z + c4.w + u4.z + d4.z;
        cnt.z = 3.0f + vc;
        sum.w = c4.z + c4.w + rgt + u4.w + d4.w;
        cnt.w = 2.0f + (hasR ? 1.0f : 0.0f) + vc;

        float4 e;
        e.x = fmaxf(0.2f * (s * sum.x + o * cnt.x) - 0.5f, 0.0f);
        e.y = fmaxf(0.2f * (s * sum.y + o * cnt.y) - 0.5f, 0.0f);
        e.z = fmaxf(0.2f * (s * sum.z + o * cnt.z) - 0.5f, 0.0f);
        e.w = fmaxf(0.2f * (s * sum.w + o * cnt.w) - 0.5f, 0.0f);

        if (store) ((float4*)op)[v] = e;

        lmin = fminf(lmin, fminf(fminf(e.x, e.y), fminf(e.z, e.w)));
        lmax = fmaxf(lmax, fmaxf(fmaxf(e.x, e.y), fmaxf(e.z, e.w)));
        lsum += (e.x + e.y) + (e.z + e.w);
    };

    ROW(u,  c0, c1, lf[0], rg[0], hasU0, true,  v0);
    ROW(c0, c1, c2, lf[1], rg[1], true,  true,  v0 + W4);
    ROW(c1, c2, c3, lf[2], rg[2], true,  true,  v0 + 2 * W4);
    ROW(c2, c3, d,  lf[3], rg[3], true,  hasD3, v0 + 3 * W4);

    // wave (64-lane) reduction
    for (int off = 32; off > 0; off >>= 1) {
        lmin = fminf(lmin, __shfl_down(lmin, off));
        lmax = fmaxf(lmax, __shfl_down(lmax, off));
        lsum += __shfl_down(lsum, off);
    }
    __shared__ float smin[4], smax[4], ssum[4];
    const int wave = threadIdx.x >> 6;
    if ((threadIdx.x & 63) == 0) { smin[wave] = lmin; smax[wave] = lmax; ssum[wave] = lsum; }
    __syncthreads();
    if (threadIdx.x == 0) {
        float bmin = smin[0], bmax = smax[0], bsum = ssum[0];
        for (int i = 1; i < 4; i++) {
            bmin = fminf(bmin, smin[i]);
            bmax = fmaxf(bmax, smax[i]);
            bsum += ssum[i];
        }
        atomicMax((unsigned*)&red[k * 32 + plane], ~__float_as_uint(bmin));
        atomicMax((int*)&red[320 + k * 32 + plane], __float_as_int(bmax));
        atomicAdd(&red[640 + k * 32 + plane], bsum);
    }
}

// One block, 64 threads: fold all 10x32 plane reductions into the scalar.
__global__ void final_out(const float* __restrict__ red, float* __restrict__ out)
{
    const int lane = threadIdx.x;
    float contrib = 0.0f;
    if (lane < 32) {
        #pragma unroll
        for (int kk = 0; kk < 10; kk++) {
            float mn = __uint_as_float(~((const unsigned*)red)[kk * 32 + lane]);
            float mx = red[320 + kk * 32 + lane];
            float sm = red[640 + kk * 32 + lane];
            float denom = mx - mn;
            float ss = 1.0f, oo = 0.0f;
            if (denom != 0.0f) { ss = 1.0f / denom; oo = -mn / denom; }
            float w = (float)((kk + 1) * (kk + 1));
            contrib += (ss * sm + oo * 262144.0f) * w;
        }
    }
    for (int off = 16; off > 0; off >>= 1)
        contrib += __shfl_down(contrib, off);
    if (lane == 0) out[0] = contrib / 8388608.0f;
}

extern "C" void kernel_launch(void* const* d_in, const int* in_sizes, int n_in,
                              void* d_out, int out_size, void* d_ws, size_t ws_size,
                              hipStream_t stream)
{
    const float* pred   = (const float*)d_in[0];
    const int*   target = (const int*)d_in[1];
    float* out  = (float*)d_out;
    float* buf0 = (float*)d_ws;
    float* buf1 = buf0 + NTOT;
    float* red  = buf1 + NTOT;

    // all reduction slots zero-init (min stored as complement)
    hipMemsetAsync((void*)red, 0, 960 * sizeof(float), stream);

    dim3 grid(64, 32);   // 64 chunks of 8 rows x 32 planes = 2048 blocks
    stencil_k<true><<<grid, 256, 0, stream>>>(nullptr, buf0, pred, target, red, 0, 1);
    const float* a = buf0;
    float*       b = buf1;
    for (int k = 1; k < 10; k++) {
        stencil_k<false><<<grid, 256, 0, stream>>>(a, b, pred, target, red, k, (k < 9) ? 1 : 0);
        const float* t = a; a = b; b = (float*)t;
    }
    final_out<<<1, 64, 0, stream>>>(red, out);
}

// Round 6
// 255.672 us; speedup vs baseline: 1.4073x; 1.4073x over previous
//
#include <hip/hip_runtime.h>

// Problem constants: B=8, C=4, H=W=512, K_ITERS=10, ALPHA=2
#define Wd   512
#define W4   128               // float4 granules per row (fp32 path)
#define W8   64                // half8 granules per row (fp16 path)
#define HWp  262144            // elements per (b,c) plane
#define NTOT 8388608           // B*C*H*W

#define F_INF __int_as_float(0x7F800000)

typedef _Float16 half8 __attribute__((ext_vector_type(8)));
typedef _Float16 half4v __attribute__((ext_vector_type(4)));

// red[] layout (960 floats, ALL zero-init; per-iteration slots):
//   cmn[k][plane] = red[k*32 + plane]        unsigned ~bits(min)
//   mx [k][plane] = red[320 + k*32 + plane]  float bits, signed atomicMax
//   sm [k][plane] = red[640 + k*32 + plane]  float atomicAdd

__device__ __forceinline__ float4 bound4(const float* __restrict__ pred,
                                         const int* __restrict__ target,
                                         int plane, int v)
{
    const int b = plane >> 2, c = plane & 3;
    float4 p = ((const float4*)(pred + (size_t)plane * HWp))[v];
    int4   t = ((const int4*)(target + (size_t)b * HWp))[v];
    float dx = p.x - (t.x == c ? 1.0f : 0.0f);
    float dy = p.y - (t.y == c ? 1.0f : 0.0f);
    float dz = p.z - (t.z == c ? 1.0f : 0.0f);
    float dw = p.w - (t.w == c ? 1.0f : 0.0f);
    return make_float4(dx*dx, dy*dy, dz*dz, dw*dw);
}

__device__ __forceinline__ float bound1(const float* __restrict__ pred,
                                        const int* __restrict__ target,
                                        int plane, int i)
{
    const int b = plane >> 2, c = plane & 3;
    float p = pred[(size_t)plane * HWp + i];
    int   t = target[(size_t)b * HWp + i];
    float d = p - (t == c ? 1.0f : 0.0f);
    return d * d;
}

__device__ __forceinline__ void block_reduce_commit(float lmin, float lmax,
                                                    float lsum,
                                                    float* __restrict__ red,
                                                    int k, int plane)
{
    for (int off = 32; off > 0; off >>= 1) {
        lmin = fminf(lmin, __shfl_down(lmin, off));
        lmax = fmaxf(lmax, __shfl_down(lmax, off));
        lsum += __shfl_down(lsum, off);
    }
    __shared__ float smin[4], smax[4], ssum[4];
    const int wave = threadIdx.x >> 6;
    if ((threadIdx.x & 63) == 0) { smin[wave] = lmin; smax[wave] = lmax; ssum[wave] = lsum; }
    __syncthreads();
    if (threadIdx.x == 0) {
        float bmin = smin[0], bmax = smax[0], bsum = ssum[0];
        for (int i = 1; i < 4; i++) {
            bmin = fminf(bmin, smin[i]);
            bmax = fmaxf(bmax, smax[i]);
            bsum += ssum[i];
        }
        atomicMax((unsigned*)&red[k * 32 + plane], ~__float_as_uint(bmin));
        atomicMax((int*)&red[320 + k * 32 + plane], __float_as_int(bmax));
        atomicAdd(&red[640 + k * 32 + plane], bsum);
    }
}

// k=0: bound from pred/target (fp32 inputs), OUTPUT stored as fp16.
// Round-4-verified structure: grid (32 chunks x 32 planes), 256 threads,
// 8 row-steps of 1 row, u/c/d loaded fresh per step, NO VGPR cap
// (rounds 3/5: capping VGPRs serializes loads -> big regressions).
// Stats are computed on the fp16-ROUNDED values so pass k+1 (which reads
// fp16) normalizes consistently.
__global__ __launch_bounds__(256) void stencil_first(const float* __restrict__ pred,
                                                     const int* __restrict__ target,
                                                     _Float16* __restrict__ out,
                                                     float* __restrict__ red)
{
    const int plane = blockIdx.y;
    const int chunk = blockIdx.x;              // 16 rows per chunk

    _Float16* op = out + (size_t)plane * HWp;

    const int col4 = threadIdx.x & 127;
    const int rsub = threadIdx.x >> 7;

    float lmin = F_INF, lmax = 0.0f, lsum = 0.0f;
    const bool hasL = (col4 > 0);
    const bool hasR = (col4 < W4 - 1);

    #pragma unroll
    for (int p = 0; p < 8; p++) {
        const int row = chunk * 16 + p * 2 + rsub;
        const int v   = row * W4 + col4;
        const bool hasU = (row > 0);
        const bool hasD = (row < Wd - 1);

        float4 c4 = bound4(pred, target, plane, v);
        float4 u4 = hasU ? bound4(pred, target, plane, v - W4) : make_float4(0,0,0,0);
        float4 d4 = hasD ? bound4(pred, target, plane, v + W4) : make_float4(0,0,0,0);
        float lft = hasL ? bound1(pred, target, plane, 4*v - 1) : 0.0f;
        float rgt = hasR ? bound1(pred, target, plane, 4*v + 4) : 0.0f;

        const float vc = (hasU ? 1.0f : 0.0f) + (hasD ? 1.0f : 0.0f);
        float4 sum, cnt;
        sum.x = c4.x + c4.y + u4.x + d4.x + lft;
        cnt.x = 2.0f + (hasL ? 1.0f : 0.0f) + vc;
        sum.y = c4.x + c4.y + c4.z + u4.y + d4.y;
        cnt.y = 3.0f + vc;
        sum.z = c4.y + c4.z + c4.w + u4.z + d4.z;
        cnt.z = 3.0f + vc;
        sum.w = c4.z + c4.w + rgt + u4.w + d4.w;
        cnt.w = 2.0f + (hasR ? 1.0f : 0.0f) + vc;

        float4 e;
        e.x = fmaxf(0.2f * sum.x - 0.5f, 0.0f);   // k=0: s=1, o=0 (cnt unused)
        e.y = fmaxf(0.2f * sum.y - 0.5f, 0.0f);
        e.z = fmaxf(0.2f * sum.z - 0.5f, 0.0f);
        e.w = fmaxf(0.2f * sum.w - 0.5f, 0.0f);
        (void)cnt;

        half4v h;
        h[0] = (_Float16)e.x; h[1] = (_Float16)e.y;
        h[2] = (_Float16)e.z; h[3] = (_Float16)e.w;
        ((half4v*)op)[v] = h;

        float r0 = (float)h[0], r1 = (float)h[1], r2 = (float)h[2], r3 = (float)h[3];
        lmin = fminf(lmin, fminf(fminf(r0, r1), fminf(r2, r3)));
        lmax = fmaxf(lmax, fmaxf(fmaxf(r0, r1), fmaxf(r2, r3)));
        lsum += (r0 + r1) + (r2 + r3);
    }

    block_reduce_commit(lmin, lmax, lsum, red, 0, plane);
}

// k>=1: fp16 in -> fp16 out, 8-wide granules (one 16B load = 8 halves).
// Same verified structure: per-step 3 vector + 2 scalar loads, 8 steps.
__global__ __launch_bounds__(256) void stencil_h(const _Float16* __restrict__ in,
                                                 _Float16* __restrict__ out,
                                                 float* __restrict__ red,
                                                 int k, int store)
{
    const int plane = blockIdx.y;
    const int chunk = blockIdx.x;              // 16 rows per chunk

    float mn = __uint_as_float(~((const unsigned*)red)[(k - 1) * 32 + plane]);
    float mx = red[320 + (k - 1) * 32 + plane];
    float denom = mx - mn;
    float s = 1.0f, o = 0.0f;
    if (denom != 0.0f) { s = 1.0f / denom; o = -mn / denom; }

    const _Float16* ip = in  + (size_t)plane * HWp;
    _Float16*       op = out + (size_t)plane * HWp;

    const int col8 = threadIdx.x & 63;         // half8 column 0..63
    const int rsub = threadIdx.x >> 6;         // 0..3

    float lmin = F_INF, lmax = 0.0f, lsum = 0.0f;
    const bool hasL = (col8 > 0);
    const bool hasR = (col8 < W8 - 1);

    #pragma unroll
    for (int p = 0; p < 4; p++) {
        const int row = chunk * 16 + p * 4 + rsub;
        const int v   = row * W8 + col8;       // plane-local half8 index
        const bool hasU = (row > 0);
        const bool hasD = (row < Wd - 1);

        half8 c8 = ((const half8*)ip)[v];
        half8 u8, d8;
        if (hasU) u8 = ((const half8*)ip)[v - W8]; else u8 = (half8)(_Float16)0;
        if (hasD) d8 = ((const half8*)ip)[v + W8]; else d8 = (half8)(_Float16)0;
        float lft = hasL ? (float)ip[8 * v - 1] : 0.0f;
        float rgt = hasR ? (float)ip[8 * v + 8] : 0.0f;

        float cf[8], uf[8], df[8];
        #pragma unroll
        for (int j = 0; j < 8; j++) {
            cf[j] = (float)c8[j]; uf[j] = (float)u8[j]; df[j] = (float)d8[j];
        }

        const float vc = (hasU ? 1.0f : 0.0f) + (hasD ? 1.0f : 0.0f);
        half8 eh;
        #pragma unroll
        for (int j = 0; j < 8; j++) {
            const float lnb = (j == 0) ? lft : cf[j - 1];
            const float rnb = (j == 7) ? rgt : cf[j + 1];
            const bool  hl  = (j > 0) || hasL;
            const bool  hr  = (j < 7) || hasR;
            float sum = cf[j] + lnb + rnb + uf[j] + df[j];
            float cnt = 1.0f + (hl ? 1.0f : 0.0f) + (hr ? 1.0f : 0.0f) + vc;
            float e = fmaxf(0.2f * (s * sum + o * cnt) - 0.5f, 0.0f);
            _Float16 h = (_Float16)e;
            eh[j] = h;
            float er = (float)h;               // rounded value for stats
            lmin = fminf(lmin, er);
            lmax = fmaxf(lmax, er);
            lsum += er;
        }

        if (store) ((half8*)op)[v] = eh;
    }

    block_reduce_commit(lmin, lmax, lsum, red, k, plane);
}

// One block, 64 threads: fold all 10x32 plane reductions into the scalar.
__global__ void final_out(const float* __restrict__ red, float* __restrict__ out)
{
    const int lane = threadIdx.x;
    float contrib = 0.0f;
    if (lane < 32) {
        #pragma unroll
        for (int kk = 0; kk < 10; kk++) {
            float mn = __uint_as_float(~((const unsigned*)red)[kk * 32 + lane]);
            float mx = red[320 + kk * 32 + lane];
            float sm = red[640 + kk * 32 + lane];
            float denom = mx - mn;
            float ss = 1.0f, oo = 0.0f;
            if (denom != 0.0f) { ss = 1.0f / denom; oo = -mn / denom; }
            float w = (float)((kk + 1) * (kk + 1));
            contrib += (ss * sm + oo * 262144.0f) * w;
        }
    }
    for (int off = 16; off > 0; off >>= 1)
        contrib += __shfl_down(contrib, off);
    if (lane == 0) out[0] = contrib / 8388608.0f;
}

extern "C" void kernel_launch(void* const* d_in, const int* in_sizes, int n_in,
                              void* d_out, int out_size, void* d_ws, size_t ws_size,
                              hipStream_t stream)
{
    const float* pred   = (const float*)d_in[0];
    const int*   target = (const int*)d_in[1];
    float* out = (float*)d_out;

    _Float16* h0  = (_Float16*)d_ws;
    _Float16* h1  = h0 + NTOT;
    float*    red = (float*)(h1 + NTOT);

    // all reduction slots zero-init (min stored as complement)
    hipMemsetAsync((void*)red, 0, 960 * sizeof(float), stream);

    dim3 grid(32, 32);   // 32 chunks of 16 rows x 32 planes (round-4 verified)
    stencil_first<<<grid, 256, 0, stream>>>(pred, target, h0, red);
    const _Float16* a = h0;
    _Float16*       b = h1;
    for (int k = 1; k < 10; k++) {
        stencil_h<<<grid, 256, 0, stream>>>(a, b, red, k, (k < 9) ? 1 : 0);
        const _Float16* t = a; a = b; b = (_Float16*)t;
    }
    final_out<<<1, 64, 0, stream>>>(red, out);
}